// Round 11
// baseline (244.836 us; speedup 1.0000x reference)
//
#include <hip/hip_runtime.h>
#include <hip/hip_bf16.h>
#include <stdint.h>

#define L_ 4
#define B_ 128
#define H_ 4096
#define BN 32
#define BKF 512               // K fetched per super-iter (2 KB/row visits, 1 KB/instr)
#define NTHR 256
#define NTOT (L_*B_*H_)       // 2,097,152 elements
#define WTB (BN*BKF*2)        // 32768 B : W tile 32 x 512 fp16 (1024 B rows)

typedef _Float16 f16x8 __attribute__((ext_vector_type(8)));
typedef float    f32x4 __attribute__((ext_vector_type(4)));
typedef float    f4    __attribute__((ext_vector_type(4)));
typedef uint32_t u32x4 __attribute__((ext_vector_type(4)));
typedef uint32_t u32x2 __attribute__((ext_vector_type(2)));

// RNE f32 -> fp16 pair packed into u32
__device__ __forceinline__ uint32_t pack2(float a, float b) {
  const _Float16 ha = (_Float16)a;
  const _Float16 hb = (_Float16)b;
  const uint32_t ua = (uint32_t)__builtin_bit_cast(uint16_t, ha);
  const uint32_t ub = (uint32_t)__builtin_bit_cast(uint16_t, hb);
  return ua | (ub << 16);
}

// ---- cvt + tile A: ws fp16 layout [kt(256)][kk(2)][lh(4)][row(128)][e(8)] ----
__global__ __launch_bounds__(NTHR)
void cvt_tile_kernel(const float* __restrict__ x, u32x4* __restrict__ ws)
{
  const int d   = blockIdx.x * NTHR + threadIdx.x;   // 0..262143
  const int row = d & 127;
  const int lh  = (d >> 7) & 3;
  const int kk  = (d >> 9) & 1;
  const int kt  = d >> 10;            // 0..255
  const int s   = kt >> 6;
  const int kb  = kt & 63;
  const float* src = x + ((size_t)(s * B_ + row)) * H_ + kb * 64 + kk * 32 + lh * 8;
  f4 lo = *reinterpret_cast<const f4*>(src);
  f4 hi = *reinterpret_cast<const f4*>(src + 4);
  u32x4 v;
  v.x = pack2(lo.x, lo.y); v.y = pack2(lo.z, lo.w);
  v.z = pack2(hi.x, hi.y); v.w = pack2(hi.z, hi.w);
  ws[d] = v;
}

// counted-wait barrier: own ds ops complete, global loads stay in flight.
__device__ __forceinline__ void bar_lgkm0() {
  __builtin_amdgcn_sched_barrier(0);
  asm volatile("s_waitcnt lgkmcnt(0)");
  __builtin_amdgcn_sched_barrier(0);
  __builtin_amdgcn_s_barrier();
  __builtin_amdgcn_sched_barrier(0);
}

// ====== main GEMM: A direct-from-tiled-ws, W 2KB-visit staged (1KB/instr); A-before-W ======
__global__ __launch_bounds__(NTHR, 2)
void net_gemm_kernel(const uint8_t* __restrict__ atiled,
                     const float* __restrict__ Wm,
                     const float* __restrict__ ext,
                     float* __restrict__ out)
{
  __shared__ __align__(16) uint8_t lds[2 * WTB];   // 64 KB: W double-buffered

  const int tid  = threadIdx.x;
  const int bid  = blockIdx.x;
  const int t    = bid >> 7;              // 0..3
  const int n0   = (bid & 127) * BN;      // output-col tile

  const int wv   = tid >> 6;              // wave 0..3
  const int lane = tid & 63;
  const int lid  = lane & 15;
  const int lh   = lane >> 4;

  // ---- A fragment base (tiled ws) ----
  const uint8_t* a_base = atiled + lh * 2048 + (wv * 32 + lid) * 16;

  // ---- W source: wave wv owns rows n0+wv*8..+7; 1KB contiguous per instruction ----
  const float* wp0 = Wm + (((size_t)t * L_) * H_ + (size_t)(n0 + wv * 8)) * H_ + (size_t)lane * 4;

  // ---- LDS read offsets for W (B-operand) fragments; rows are 1024 B ----
  uint32_t b_rd[2][2];
  #pragma unroll
  for (int nf = 0; nf < 2; ++nf)
    #pragma unroll
    for (int kk = 0; kk < 2; ++kk) {
      const uint32_t row = (uint32_t)(nf * 16 + lid);
      b_rd[nf][kk] = row * 1024 +
                     (((uint32_t)(kk * 64 + lh * 16)) ^ (((uint32_t)lid & 7) << 4));
    }

  f32x4 acc[2][2] = {};

  f4    wR[16];                             // W reg staging (64 VGPR)
  f16x8 aP[2][2], aQ[2][2], aR_[2][2], aS_[2][2];   // A rotation: substep s uses set s%4

  auto LOADW = [&](int j, f4 (&w)[16]) {
    const float* p = wp0 + (size_t)(j >> 3) * ((size_t)H_ * H_) + ((j & 7) << 9);
    #pragma unroll
    for (int i = 0; i < 8; ++i) {
      w[2*i]   = __builtin_nontemporal_load(reinterpret_cast<const f4*>(p + (size_t)i * H_));
      w[2*i+1] = __builtin_nontemporal_load(reinterpret_cast<const f4*>(p + (size_t)i * H_ + 256));
    }
  };

  auto WRITEW = [&](uint8_t* base, f4 (&w)[16]) {
    #pragma unroll
    for (int i = 0; i < 8; ++i) {
      u32x2 v0, v1;
      v0.x = pack2(w[2*i].x,   w[2*i].y);   v0.y = pack2(w[2*i].z,   w[2*i].w);
      v1.x = pack2(w[2*i+1].x, w[2*i+1].y); v1.y = pack2(w[2*i+1].z, w[2*i+1].w);
      const uint32_t off = (uint32_t)(wv * 8 + i) * 1024 +
                           (((uint32_t)lane * 8) ^ ((uint32_t)i << 4));
      *reinterpret_cast<u32x2*>(base + off) = v0;
      *reinterpret_cast<u32x2*>(base + off + 512) = v1;
    }
  };

  auto LOADA = [&](int kt, f16x8 (&a)[2][2]) {
    const uint8_t* p = a_base + (size_t)kt * 16384;
    a[0][0] = *reinterpret_cast<const f16x8*>(p);
    a[1][0] = *reinterpret_cast<const f16x8*>(p + 256);
    a[0][1] = *reinterpret_cast<const f16x8*>(p + 8192);
    a[1][1] = *reinterpret_cast<const f16x8*>(p + 8192 + 256);
  };

  auto SUB = [&](const uint8_t* base, int skoff, f16x8 (&av)[2][2]) {
    f16x8 bv[2][2];
    #pragma unroll
    for (int nf = 0; nf < 2; ++nf)
      #pragma unroll
      for (int kk = 0; kk < 2; ++kk)
        bv[nf][kk] = *reinterpret_cast<const f16x8*>(base + b_rd[nf][kk] + skoff);
    #pragma unroll
    for (int kk = 0; kk < 2; ++kk)
      #pragma unroll
      for (int mf = 0; mf < 2; ++mf)
        #pragma unroll
        for (int nf = 0; nf < 2; ++nf)
          acc[mf][nf] = __builtin_amdgcn_mfma_f32_16x16x32_f16(
              av[mf][kk], bv[nf][kk], acc[mf][nf], 0, 0, 0);
  };

  uint8_t* buf0 = lds;
  uint8_t* buf1 = lds + WTB;

  // prologue: chunk 0 -> buf0; A(0) prefetched (stays in flight past WRITEW's wait)
  LOADW(0, wR);
  LOADA(0, aP);
  WRITEW(buf0, wR);          // reg-dep drains W0 only (counted vmcnt)
  bar_lgkm0();

  // ITER j (k-tiles 8j..8j+7 from BC_): A(8j+1..3) issued BEFORE W(j+1) burst;
  // remaining A loads interleaved after subs; W drains only at WRITEW (iter end).
  #define ITER(j_, BC_, BW_) do {                         \
      LOADA(8*(j_) + 1, aQ);                              \
      LOADA(8*(j_) + 2, aR_);                             \
      LOADA(8*(j_) + 3, aS_);                             \
      __builtin_amdgcn_sched_barrier(0);                  \
      LOADW((j_) + 1, wR);                                \
      __builtin_amdgcn_sched_barrier(0);                  \
      SUB(BC_, 0, aP);    LOADA(8*(j_) + 4, aP);          \
      SUB(BC_, 128, aQ);  LOADA(8*(j_) + 5, aQ);          \
      SUB(BC_, 256, aR_); LOADA(8*(j_) + 6, aR_);         \
      SUB(BC_, 384, aS_); LOADA(8*(j_) + 7, aS_);         \
      SUB(BC_, 512, aP);  LOADA(8*(j_) + 8, aP);          \
      SUB(BC_, 640, aQ);                                  \
      SUB(BC_, 768, aR_);                                 \
      SUB(BC_, 896, aS_);                                 \
      WRITEW(BW_, wR);                                    \
      bar_lgkm0();                                        \
    } while (0)

  #pragma unroll 1
  for (int jj = 0; jj < 30; jj += 2) {
    ITER(jj,     buf0, buf1);
    ITER(jj + 1, buf1, buf0);
  }
  ITER(30, buf0, buf1);          // stages chunk 31 -> buf1; A(248)->aP
  #undef ITER

  // tail j = 31: compute only (chunk 31 in buf1), k-tiles 248..255
  LOADA(249, aQ);
  LOADA(250, aR_);
  LOADA(251, aS_);
  SUB(buf1, 0, aP);    LOADA(252, aP);
  SUB(buf1, 128, aQ);  LOADA(253, aQ);
  SUB(buf1, 256, aR_); LOADA(254, aR_);
  SUB(buf1, 384, aS_); LOADA(255, aS_);
  SUB(buf1, 512, aP);
  SUB(buf1, 640, aQ);
  SUB(buf1, 768, aR_);
  SUB(buf1, 896, aS_);

  // ---- epilogue: out = tanh(acc + ext), C/D layout col=lane&15, row=lh*4+j ----
  #pragma unroll
  for (int mf = 0; mf < 2; ++mf)
    #pragma unroll
    for (int nf = 0; nf < 2; ++nf)
      #pragma unroll
      for (int j = 0; j < 4; ++j) {
        const int brow = wv * 32 + mf * 16 + lh * 4 + j;
        const int ocol = n0 + nf * 16 + lid;
        const size_t idx = ((size_t)(t * B_ + brow)) * H_ + ocol;
        out[idx] = tanhf(acc[mf][nf][j] + ext[idx]);
      }
}

// ================= fallback (no ws): R3 structure, f32 A + cvt in-kernel =================
#define FBK 64
#define FB_ABYTES (128*FBK*2)
#define FB_WBYTES (BN*FBK*2)
#define FB_BUFB   (FB_ABYTES+FB_WBYTES)
__global__ __launch_bounds__(NTHR, 2)
void net_gemm_fb(const float* __restrict__ statesf,
                 const float* __restrict__ Wm,
                 const float* __restrict__ ext,
                 float* __restrict__ out)
{
  __shared__ __align__(16) uint8_t lds[2 * FB_BUFB];

  const int tid  = threadIdx.x;
  const int bid  = blockIdx.x;
  const int t    = bid >> 7;
  const int n0   = (bid & 127) * BN;
  const int wv   = tid >> 6;
  const int lane = tid & 63;
  const int lid  = lane & 15;
  const int lh   = lane >> 4;

  const int arow = tid >> 3;
  const int acol = (tid & 7) * 8;
  const uint32_t a_st_off =
      (uint32_t)arow * 128 + (((uint32_t)(tid & 7) * 16) ^ ((uint32_t)(arow & 7) << 4));
  const float* af_base = statesf + (size_t)arow * H_ + acol;

  const int wrow = tid >> 4;
  const int wcol = (tid & 15) * 4;
  const float* w_base = Wm + ((size_t)t * L_ * H_ + (size_t)(n0 + wrow)) * H_ + wcol;
  const uint32_t w_st0 =
      (uint32_t)FB_ABYTES + (uint32_t)wrow * 128 + (((uint32_t)(tid & 15) * 8) ^ ((uint32_t)(wrow & 7) << 4));
  const uint32_t w_st1 = w_st0 + 16 * 128;

  uint32_t a_rd[2][2], b_rd[2][2];
  #pragma unroll
  for (int mf = 0; mf < 2; ++mf)
    #pragma unroll
    for (int kk = 0; kk < 2; ++kk) {
      const int row = wv * 32 + mf * 16 + lid;
      a_rd[mf][kk] = (uint32_t)row * 128 +
                     (((uint32_t)(kk * 64 + lh * 16)) ^ ((uint32_t)(lid & 7) << 4));
    }
  #pragma unroll
  for (int nf = 0; nf < 2; ++nf)
    #pragma unroll
    for (int kk = 0; kk < 2; ++kk) {
      const int row = nf * 16 + lid;
      b_rd[nf][kk] = (uint32_t)FB_ABYTES + (uint32_t)row * 128 +
                     (((uint32_t)(kk * 64 + lh * 16)) ^ ((uint32_t)(lid & 7) << 4));
    }

  f32x4 acc[2][2] = {};
  f4 af0[4][2], af1[4][2], wf0[2], wf1[2];

  auto LOADg = [&](int kidx, f4 (&af)[4][2], f4 (&wfx)[2]) {
    const int s  = kidx >> 6;
    const int h0 = (kidx & 63) << 6;
    const float* ap = af_base + (size_t)s * (B_ * H_) + h0;
    #pragma unroll
    for (int j = 0; j < 4; ++j) {
      af[j][0] = *reinterpret_cast<const f4*>(ap + (size_t)j * (32 * H_));
      af[j][1] = *reinterpret_cast<const f4*>(ap + (size_t)j * (32 * H_) + 4);
    }
    const float* wp = w_base + (size_t)s * ((size_t)H_ * H_) + h0;
    wfx[0] = __builtin_nontemporal_load(reinterpret_cast<const f4*>(wp));
    wfx[1] = __builtin_nontemporal_load(reinterpret_cast<const f4*>(wp + 16 * (size_t)H_));
  };

  auto WRITEg = [&](uint8_t* base, f4 (&af)[4][2], f4 (&wfx)[2]) {
    #pragma unroll
    for (int j = 0; j < 4; ++j) {
      u32x4 v;
      v.x = pack2(af[j][0].x, af[j][0].y);
      v.y = pack2(af[j][0].z, af[j][0].w);
      v.z = pack2(af[j][1].x, af[j][1].y);
      v.w = pack2(af[j][1].z, af[j][1].w);
      *reinterpret_cast<u32x4*>(base + j * 4096 + a_st_off) = v;
    }
    u32x2 w0, w1;
    w0.x = pack2(wfx[0].x, wfx[0].y); w0.y = pack2(wfx[0].z, wfx[0].w);
    w1.x = pack2(wfx[1].x, wfx[1].y); w1.y = pack2(wfx[1].z, wfx[1].w);
    *reinterpret_cast<u32x2*>(base + w_st0) = w0;
    *reinterpret_cast<u32x2*>(base + w_st1) = w1;
  };

  auto COMPUTE = [&](const uint8_t* base) {
    f16x8 av[2][2], bv[2][2];
    #pragma unroll
    for (int mf = 0; mf < 2; ++mf)
      #pragma unroll
      for (int kk = 0; kk < 2; ++kk)
        av[mf][kk] = *reinterpret_cast<const f16x8*>(base + a_rd[mf][kk]);
    #pragma unroll
    for (int nf = 0; nf < 2; ++nf)
      #pragma unroll
      for (int kk = 0; kk < 2; ++kk)
        bv[nf][kk] = *reinterpret_cast<const f16x8*>(base + b_rd[nf][kk]);
    #pragma unroll
    for (int kk = 0; kk < 2; ++kk)
      #pragma unroll
      for (int mf = 0; mf < 2; ++mf)
        #pragma unroll
        for (int nf = 0; nf < 2; ++nf)
          acc[mf][nf] = __builtin_amdgcn_mfma_f32_16x16x32_f16(
              av[mf][kk], bv[nf][kk], acc[mf][nf], 0, 0, 0);
  };

  uint8_t* buf0 = lds;
  uint8_t* buf1 = lds + FB_BUFB;

  LOADg(0, af0, wf0);
  LOADg(1, af1, wf1);
  WRITEg(buf0, af0, wf0);
  bar_lgkm0();

  #pragma unroll 1
  for (int k = 0; k < 256; k += 2) {
    if (k + 2 < 256) LOADg(k + 2, af0, wf0);
    COMPUTE(buf0);
    WRITEg(buf1, af1, wf1);
    bar_lgkm0();
    if (k + 3 < 256) LOADg(k + 3, af1, wf1);
    COMPUTE(buf1);
    if (k + 2 < 256) {
      WRITEg(buf0, af0, wf0);
      bar_lgkm0();
    }
  }

  #pragma unroll
  for (int mf = 0; mf < 2; ++mf)
    #pragma unroll
    for (int nf = 0; nf < 2; ++nf)
      #pragma unroll
      for (int j = 0; j < 4; ++j) {
        const int brow = wv * 32 + mf * 16 + lh * 4 + j;
        const int ocol = n0 + nf * 16 + lid;
        const size_t idx = ((size_t)(t * B_ + brow)) * H_ + ocol;
        out[idx] = tanhf(acc[mf][nf][j] + ext[idx]);
      }
}

extern "C" void kernel_launch(void* const* d_in, const int* in_sizes, int n_in,
                              void* d_out, int out_size, void* d_ws, size_t ws_size,
                              hipStream_t stream) {
  const float* states = (const float*)d_in[0];
  const float* W      = (const float*)d_in[1];
  const float* ext    = (const float*)d_in[2];
  float* out          = (float*)d_out;

  const size_t st_bytes = (size_t)NTOT * 2;          // 4,194,304 : fp16 tiled states
  if (ws_size >= st_bytes) {
    const int nunits = NTOT / 8;                     // 262,144 16-B units
    cvt_tile_kernel<<<nunits / NTHR, NTHR, 0, stream>>>(states, (u32x4*)d_ws);
    net_gemm_kernel<<<512, NTHR, 0, stream>>>(
        (const uint8_t*)d_ws, W, ext, out);
  } else {
    net_gemm_fb<<<512, NTHR, 0, stream>>>(states, W, ext, out);
  }
}

// Round 12
// 212.560 us; speedup vs baseline: 1.1518x; 1.1518x over previous
//
#include <hip/hip_runtime.h>
#include <hip/hip_bf16.h>
#include <stdint.h>

#define L_ 4
#define B_ 128
#define H_ 4096
#define BN 32
#define BKF 256               // K fetched per super-iter (1 KB/row chunks) — proven optimum
#define NTHR 256
#define NTOT (L_*B_*H_)       // 2,097,152 elements
#define WTB (BN*BKF*2)        // 16384 B : W tile 32 x 256 fp16 (512 B rows)

typedef _Float16 f16x8 __attribute__((ext_vector_type(8)));
typedef float    f32x4 __attribute__((ext_vector_type(4)));
typedef float    f4    __attribute__((ext_vector_type(4)));
typedef uint32_t u32x4 __attribute__((ext_vector_type(4)));
typedef uint32_t u32x2 __attribute__((ext_vector_type(2)));

// RNE f32 -> fp16 pair packed into u32
__device__ __forceinline__ uint32_t pack2(float a, float b) {
  const _Float16 ha = (_Float16)a;
  const _Float16 hb = (_Float16)b;
  const uint32_t ua = (uint32_t)__builtin_bit_cast(uint16_t, ha);
  const uint32_t ub = (uint32_t)__builtin_bit_cast(uint16_t, hb);
  return ua | (ub << 16);
}

// ---- cvt + tile A: ws fp16 layout [kt(256)][kk(2)][lh(4)][row(128)][e(8)] ----
__global__ __launch_bounds__(NTHR)
void cvt_tile_kernel(const float* __restrict__ x, u32x4* __restrict__ ws)
{
  const int d   = blockIdx.x * NTHR + threadIdx.x;   // 0..262143
  const int row = d & 127;
  const int lh  = (d >> 7) & 3;
  const int kk  = (d >> 9) & 1;
  const int kt  = d >> 10;            // 0..255
  const int s   = kt >> 6;
  const int kb  = kt & 63;
  const float* src = x + ((size_t)(s * B_ + row)) * H_ + kb * 64 + kk * 32 + lh * 8;
  f4 lo = *reinterpret_cast<const f4*>(src);
  f4 hi = *reinterpret_cast<const f4*>(src + 4);
  u32x4 v;
  v.x = pack2(lo.x, lo.y); v.y = pack2(lo.z, lo.w);
  v.z = pack2(hi.x, hi.y); v.w = pack2(hi.z, hi.w);
  ws[d] = v;
}

// counted-wait barrier: own ds ops complete, global loads stay in flight.
__device__ __forceinline__ void bar_lgkm0() {
  __builtin_amdgcn_sched_barrier(0);
  asm volatile("s_waitcnt lgkmcnt(0)");
  __builtin_amdgcn_sched_barrier(0);
  __builtin_amdgcn_s_barrier();
  __builtin_amdgcn_sched_barrier(0);
}

// ====== main GEMM: A direct-from-tiled-ws, W 1KB-row staged; A-before-W issue order ======
__global__ __launch_bounds__(NTHR, 2)
void net_gemm_kernel(const uint8_t* __restrict__ atiled,
                     const float* __restrict__ Wm,
                     const float* __restrict__ ext,
                     float* __restrict__ out)
{
  __shared__ __align__(16) uint8_t lds[2 * WTB];   // 32 KB: W double-buffered

  const int tid  = threadIdx.x;
  const int bid  = blockIdx.x;
  const int t    = bid >> 7;              // 0..3
  const int n0   = (bid & 127) * BN;      // output-col tile

  const int wv   = tid >> 6;              // wave 0..3
  const int lane = tid & 63;
  const int lid  = lane & 15;
  const int lh   = lane >> 4;

  // ---- A fragment base (tiled ws) ----
  const uint8_t* a_base = atiled + lh * 2048 + (wv * 32 + lid) * 16;

  // ---- W source: wave wv owns rows n0+wv*8..+7; one contiguous 1KB row per instr ----
  const float* wp0 = Wm + (((size_t)t * L_) * H_ + (size_t)(n0 + wv * 8)) * H_ + (size_t)lane * 4;

  // ---- LDS read offsets for W (B-operand) fragments; rows are 512 B ----
  uint32_t b_rd[2][2];
  #pragma unroll
  for (int nf = 0; nf < 2; ++nf)
    #pragma unroll
    for (int kk = 0; kk < 2; ++kk) {
      const uint32_t row = (uint32_t)(nf * 16 + lid);
      b_rd[nf][kk] = row * 512 +
                     (((uint32_t)(kk * 64 + lh * 16)) ^ (((uint32_t)lid & 7) << 4));
    }

  f32x4 acc[2][2] = {};

  f4    wR[8];                              // W reg staging (32 VGPR)
  f16x8 aP[2][2], aQ[2][2], aR_[2][2], aS_[2][2];   // A sets for substeps 0..3

  auto LOADW = [&](int j, f4 (&w)[8]) {
    const float* p = wp0 + (size_t)(j >> 4) * ((size_t)H_ * H_) + ((j & 15) << 8);
    #pragma unroll
    for (int i = 0; i < 8; ++i)
      w[i] = __builtin_nontemporal_load(reinterpret_cast<const f4*>(p + (size_t)i * H_));
  };

  auto WRITEW = [&](uint8_t* base, f4 (&w)[8]) {
    #pragma unroll
    for (int i = 0; i < 8; ++i) {
      u32x2 v;
      v.x = pack2(w[i].x, w[i].y);
      v.y = pack2(w[i].z, w[i].w);
      const uint32_t off = (uint32_t)wv * 4096 + (uint32_t)i * 512 +
                           (((uint32_t)lane * 8) ^ ((uint32_t)i << 4));
      *reinterpret_cast<u32x2*>(base + off) = v;
    }
  };

  auto LOADA = [&](int kt, f16x8 (&a)[2][2]) {
    const uint8_t* p = a_base + (size_t)kt * 16384;
    a[0][0] = *reinterpret_cast<const f16x8*>(p);
    a[1][0] = *reinterpret_cast<const f16x8*>(p + 256);
    a[0][1] = *reinterpret_cast<const f16x8*>(p + 8192);
    a[1][1] = *reinterpret_cast<const f16x8*>(p + 8192 + 256);
  };

  auto SUB = [&](const uint8_t* base, int skoff, f16x8 (&av)[2][2]) {
    f16x8 bv[2][2];
    #pragma unroll
    for (int nf = 0; nf < 2; ++nf)
      #pragma unroll
      for (int kk = 0; kk < 2; ++kk)
        bv[nf][kk] = *reinterpret_cast<const f16x8*>(base + b_rd[nf][kk] + skoff);
    #pragma unroll
    for (int kk = 0; kk < 2; ++kk)
      #pragma unroll
      for (int mf = 0; mf < 2; ++mf)
        #pragma unroll
        for (int nf = 0; nf < 2; ++nf)
          acc[mf][nf] = __builtin_amdgcn_mfma_f32_16x16x32_f16(
              av[mf][kk], bv[nf][kk], acc[mf][nf], 0, 0, 0);
  };

  uint8_t* buf0 = lds;
  uint8_t* buf1 = lds + WTB;

  // prologue: chunk 0 -> buf0; A(0) prefetched (stays in flight past WRITEW's wait)
  LOADW(0, wR);
  LOADA(0, aP);
  WRITEW(buf0, wR);          // reg-dep drains W0 only (counted vmcnt)
  bar_lgkm0();

  // ---- ext prefetch: 16 scattered values loaded once, retire under early iters ----
  float extv[2][2][4];
  #pragma unroll
  for (int mf = 0; mf < 2; ++mf)
    #pragma unroll
    for (int nf = 0; nf < 2; ++nf)
      #pragma unroll
      for (int j = 0; j < 4; ++j) {
        const int brow = wv * 32 + mf * 16 + lh * 4 + j;
        const int ocol = n0 + nf * 16 + lid;
        extv[mf][nf][j] = ext[((size_t)(t * B_ + brow)) * H_ + ocol];
      }

  // ITER j: [issue A(4j+1..3)] [issue W(j+1)] sub0(aP) [issue A(4j+4)->aP]
  //         sub1..3  WRITEW(chunk j+1 -> BW)  bar
  // A issued BEFORE W => substep vmcnt waits leave the W burst in flight all iter.
  #define ITER(j_, BC_, BW_, LNEXT_) do {                 \
      LOADA(4*(j_) + 1, aQ);                              \
      LOADA(4*(j_) + 2, aR_);                             \
      LOADA(4*(j_) + 3, aS_);                             \
      __builtin_amdgcn_sched_barrier(0);                  \
      LOADW((j_) + 1, wR);                                \
      __builtin_amdgcn_sched_barrier(0);                  \
      SUB(BC_, 0, aP);                                    \
      if (LNEXT_) LOADA(4*(j_) + 4, aP);                  \
      SUB(BC_, 128, aQ);                                  \
      SUB(BC_, 256, aR_);                                 \
      SUB(BC_, 384, aS_);                                 \
      WRITEW(BW_, wR);                                    \
      bar_lgkm0();                                        \
    } while (0)

  #pragma unroll 1
  for (int jj = 0; jj < 62; jj += 2) {
    ITER(jj,     buf0, buf1, 1);
    ITER(jj + 1, buf1, buf0, 1);
  }
  ITER(62, buf0, buf1, 1);       // loads chunk 63 -> buf1; A(252)->aP

  // j = 63: compute only (chunk 63 in buf1)
  LOADA(253, aQ);
  LOADA(254, aR_);
  LOADA(255, aS_);
  SUB(buf1, 0,   aP);
  SUB(buf1, 128, aQ);
  SUB(buf1, 256, aR_);
  SUB(buf1, 384, aS_);
  #undef ITER

  // ---- epilogue: out = tanh(acc + extv), C/D layout col=lane&15, row=lh*4+j ----
  #pragma unroll
  for (int mf = 0; mf < 2; ++mf)
    #pragma unroll
    for (int nf = 0; nf < 2; ++nf)
      #pragma unroll
      for (int j = 0; j < 4; ++j) {
        const int brow = wv * 32 + mf * 16 + lh * 4 + j;
        const int ocol = n0 + nf * 16 + lid;
        const size_t idx = ((size_t)(t * B_ + brow)) * H_ + ocol;
        out[idx] = tanhf(acc[mf][nf][j] + extv[mf][nf][j]);
      }
}

// ================= fallback (no ws): R3 structure, f32 A + cvt in-kernel =================
#define FBK 64
#define FB_ABYTES (128*FBK*2)
#define FB_WBYTES (BN*FBK*2)
#define FB_BUFB   (FB_ABYTES+FB_WBYTES)
__global__ __launch_bounds__(NTHR, 2)
void net_gemm_fb(const float* __restrict__ statesf,
                 const float* __restrict__ Wm,
                 const float* __restrict__ ext,
                 float* __restrict__ out)
{
  __shared__ __align__(16) uint8_t lds[2 * FB_BUFB];

  const int tid  = threadIdx.x;
  const int bid  = blockIdx.x;
  const int t    = bid >> 7;
  const int n0   = (bid & 127) * BN;
  const int wv   = tid >> 6;
  const int lane = tid & 63;
  const int lid  = lane & 15;
  const int lh   = lane >> 4;

  const int arow = tid >> 3;
  const int acol = (tid & 7) * 8;
  const uint32_t a_st_off =
      (uint32_t)arow * 128 + (((uint32_t)(tid & 7) * 16) ^ ((uint32_t)(arow & 7) << 4));
  const float* af_base = statesf + (size_t)arow * H_ + acol;

  const int wrow = tid >> 4;
  const int wcol = (tid & 15) * 4;
  const float* w_base = Wm + ((size_t)t * L_ * H_ + (size_t)(n0 + wrow)) * H_ + wcol;
  const uint32_t w_st0 =
      (uint32_t)FB_ABYTES + (uint32_t)wrow * 128 + (((uint32_t)(tid & 15) * 8) ^ ((uint32_t)(wrow & 7) << 4));
  const uint32_t w_st1 = w_st0 + 16 * 128;

  uint32_t a_rd[2][2], b_rd[2][2];
  #pragma unroll
  for (int mf = 0; mf < 2; ++mf)
    #pragma unroll
    for (int kk = 0; kk < 2; ++kk) {
      const int row = wv * 32 + mf * 16 + lid;
      a_rd[mf][kk] = (uint32_t)row * 128 +
                     (((uint32_t)(kk * 64 + lh * 16)) ^ ((uint32_t)(lid & 7) << 4));
    }
  #pragma unroll
  for (int nf = 0; nf < 2; ++nf)
    #pragma unroll
    for (int kk = 0; kk < 2; ++kk) {
      const int row = nf * 16 + lid;
      b_rd[nf][kk] = (uint32_t)FB_ABYTES + (uint32_t)row * 128 +
                     (((uint32_t)(kk * 64 + lh * 16)) ^ ((uint32_t)(lid & 7) << 4));
    }

  f32x4 acc[2][2] = {};
  f4 af0[4][2], af1[4][2], wf0[2], wf1[2];

  auto LOADg = [&](int kidx, f4 (&af)[4][2], f4 (&wfx)[2]) {
    const int s  = kidx >> 6;
    const int h0 = (kidx & 63) << 6;
    const float* ap = af_base + (size_t)s * (B_ * H_) + h0;
    #pragma unroll
    for (int j = 0; j < 4; ++j) {
      af[j][0] = *reinterpret_cast<const f4*>(ap + (size_t)j * (32 * H_));
      af[j][1] = *reinterpret_cast<const f4*>(ap + (size_t)j * (32 * H_) + 4);
    }
    const float* wp = w_base + (size_t)s * ((size_t)H_ * H_) + h0;
    wfx[0] = __builtin_nontemporal_load(reinterpret_cast<const f4*>(wp));
    wfx[1] = __builtin_nontemporal_load(reinterpret_cast<const f4*>(wp + 16 * (size_t)H_));
  };

  auto WRITEg = [&](uint8_t* base, f4 (&af)[4][2], f4 (&wfx)[2]) {
    #pragma unroll
    for (int j = 0; j < 4; ++j) {
      u32x4 v;
      v.x = pack2(af[j][0].x, af[j][0].y);
      v.y = pack2(af[j][0].z, af[j][0].w);
      v.z = pack2(af[j][1].x, af[j][1].y);
      v.w = pack2(af[j][1].z, af[j][1].w);
      *reinterpret_cast<u32x4*>(base + j * 4096 + a_st_off) = v;
    }
    u32x2 w0, w1;
    w0.x = pack2(wfx[0].x, wfx[0].y); w0.y = pack2(wfx[0].z, wfx[0].w);
    w1.x = pack2(wfx[1].x, wfx[1].y); w1.y = pack2(wfx[1].z, wfx[1].w);
    *reinterpret_cast<u32x2*>(base + w_st0) = w0;
    *reinterpret_cast<u32x2*>(base + w_st1) = w1;
  };

  auto COMPUTE = [&](const uint8_t* base) {
    f16x8 av[2][2], bv[2][2];
    #pragma unroll
    for (int mf = 0; mf < 2; ++mf)
      #pragma unroll
      for (int kk = 0; kk < 2; ++kk)
        av[mf][kk] = *reinterpret_cast<const f16x8*>(base + a_rd[mf][kk]);
    #pragma unroll
    for (int nf = 0; nf < 2; ++nf)
      #pragma unroll
      for (int kk = 0; kk < 2; ++kk)
        bv[nf][kk] = *reinterpret_cast<const f16x8*>(base + b_rd[nf][kk]);
    #pragma unroll
    for (int kk = 0; kk < 2; ++kk)
      #pragma unroll
      for (int mf = 0; mf < 2; ++mf)
        #pragma unroll
        for (int nf = 0; nf < 2; ++nf)
          acc[mf][nf] = __builtin_amdgcn_mfma_f32_16x16x32_f16(
              av[mf][kk], bv[nf][kk], acc[mf][nf], 0, 0, 0);
  };

  uint8_t* buf0 = lds;
  uint8_t* buf1 = lds + FB_BUFB;

  LOADg(0, af0, wf0);
  LOADg(1, af1, wf1);
  WRITEg(buf0, af0, wf0);
  bar_lgkm0();

  #pragma unroll 1
  for (int k = 0; k < 256; k += 2) {
    if (k + 2 < 256) LOADg(k + 2, af0, wf0);
    COMPUTE(buf0);
    WRITEg(buf1, af1, wf1);
    bar_lgkm0();
    if (k + 3 < 256) LOADg(k + 3, af1, wf1);
    COMPUTE(buf1);
    if (k + 2 < 256) {
      WRITEg(buf0, af0, wf0);
      bar_lgkm0();
    }
  }

  #pragma unroll
  for (int mf = 0; mf < 2; ++mf)
    #pragma unroll
    for (int nf = 0; nf < 2; ++nf)
      #pragma unroll
      for (int j = 0; j < 4; ++j) {
        const int brow = wv * 32 + mf * 16 + lh * 4 + j;
        const int ocol = n0 + nf * 16 + lid;
        const size_t idx = ((size_t)(t * B_ + brow)) * H_ + ocol;
        out[idx] = tanhf(acc[mf][nf][j] + ext[idx]);
      }
}

extern "C" void kernel_launch(void* const* d_in, const int* in_sizes, int n_in,
                              void* d_out, int out_size, void* d_ws, size_t ws_size,
                              hipStream_t stream) {
  const float* states = (const float*)d_in[0];
  const float* W      = (const float*)d_in[1];
  const float* ext    = (const float*)d_in[2];
  float* out          = (float*)d_out;

  const size_t st_bytes = (size_t)NTOT * 2;          // 4,194,304 : fp16 tiled states
  if (ws_size >= st_bytes) {
    const int nunits = NTOT / 8;                     // 262,144 16-B units
    cvt_tile_kernel<<<nunits / NTHR, NTHR, 0, stream>>>(states, (u32x4*)d_ws);
    net_gemm_kernel<<<512, NTHR, 0, stream>>>(
        (const uint8_t*)d_ws, W, ext, out);
  } else {
    net_gemm_fb<<<512, NTHR, 0, stream>>>(states, W, ext, out);
  }
}